// Round 14
// baseline (839.795 us; speedup 1.0000x reference)
//
#include <hip/hip_runtime.h>
#include <math.h>

typedef unsigned short u16;
typedef short bf16x8 __attribute__((ext_vector_type(8)));
typedef float f32x4 __attribute__((ext_vector_type(4)));

#define HID 2048
#define NH 16
#define HD 128
#define LI 2048
#define LT 256
#define LA 2304
#define MODW 12288

__device__ __forceinline__ u16 f2bf(float f) {
  unsigned int u = __float_as_uint(f);
  u += 0x7fff + ((u >> 16) & 1);   // round-to-nearest-even
  return (u16)(u >> 16);
}
__device__ __forceinline__ float bf2f(u16 b) {
  return __uint_as_float(((unsigned int)b) << 16);
}

__device__ __forceinline__ void gload16(const void* g, void* l) {
  __builtin_amdgcn_global_load_lds(
      (const __attribute__((address_space(1))) unsigned int*)g,
      (__attribute__((address_space(3))) unsigned int*)l, 16, 0, 0);
}

// ---------------- modulation GEMV: silu(vec) @ mod_w ----------------
__global__ void k_mod_partial(const float* __restrict__ vec,
                              const float* __restrict__ wi,
                              const float* __restrict__ wt,
                              float* __restrict__ part) {
  __shared__ float sv[256];
  int j = blockIdx.x * 256 + threadIdx.x;
  int k0 = blockIdx.y * 256;
  const float* w = blockIdx.z ? wt : wi;
  float v = vec[k0 + threadIdx.x];
  sv[threadIdx.x] = v / (1.f + expf(-v));
  __syncthreads();
  float acc = 0.f;
  for (int kk = 0; kk < 256; ++kk)
    acc += sv[kk] * w[(size_t)(k0 + kk) * MODW + j];
  part[(size_t)(blockIdx.z * 8 + blockIdx.y) * MODW + j] = acc;
}

__global__ void k_mod_reduce(const float* __restrict__ part,
                             const float* __restrict__ bi,
                             const float* __restrict__ bt,
                             float* __restrict__ mod) {
  int i = blockIdx.x * 256 + threadIdx.x;   // 0..24575
  int s = i / MODW, j = i % MODW;
  const float* b = s ? bt : bi;
  float v = b[j];
#pragma unroll
  for (int c = 0; c < 8; ++c) v += part[(size_t)(s * 8 + c) * MODW + j];
  mod[i] = v;
}

// ------- LayerNorm + (1+sc)*x + sh -> bf16, merged [txt; img] rows -------
__global__ void k_ln_mod(const float* __restrict__ xi, const float* __restrict__ xt,
                         const float* __restrict__ shi, const float* __restrict__ sci,
                         const float* __restrict__ sht, const float* __restrict__ sct,
                         u16* __restrict__ out) {
  int r = blockIdx.x;                 // merged row: txt first
  bool txs = r < LT;
  const float* xr = txs ? (xt + (size_t)r * HID) : (xi + (size_t)(r - LT) * HID);
  const float* sh = txs ? sht : shi;
  const float* sc = txs ? sct : sci;
  float4 v0 = ((const float4*)xr)[threadIdx.x * 2];
  float4 v1 = ((const float4*)xr)[threadIdx.x * 2 + 1];
  float s1 = v0.x + v0.y + v0.z + v0.w + v1.x + v1.y + v1.z + v1.w;
  float s2 = v0.x * v0.x + v0.y * v0.y + v0.z * v0.z + v0.w * v0.w +
             v1.x * v1.x + v1.y * v1.y + v1.z * v1.z + v1.w * v1.w;
#pragma unroll
  for (int m = 1; m < 64; m <<= 1) { s1 += __shfl_xor(s1, m); s2 += __shfl_xor(s2, m); }
  __shared__ float red[8];
  int wid = threadIdx.x >> 6;
  if ((threadIdx.x & 63) == 0) { red[wid] = s1; red[4 + wid] = s2; }
  __syncthreads();
  float tot  = red[0] + red[1] + red[2] + red[3];
  float tot2 = red[4] + red[5] + red[6] + red[7];
  float mu = tot * (1.f / HID);
  float var = tot2 * (1.f / HID) - mu * mu;
  float rs = rsqrtf(var + 1e-6f);
  int c = threadIdx.x * 8;
  float v[8] = {v0.x, v0.y, v0.z, v0.w, v1.x, v1.y, v1.z, v1.w};
  u16 o[8] __attribute__((aligned(16)));
#pragma unroll
  for (int u = 0; u < 8; ++u)
    o[u] = f2bf((v[u] - mu) * rs * (1.f + sc[c + u]) + sh[c + u]);
  *(uint4*)&out[(size_t)r * HID + c] = *(uint4*)o;
}

// ----- 128x128 GEMM, m97 structure, B = f32 [K][N] weights with fused -----
// ----- transpose+convert staged via registers (tconv eliminated).      -----
// MODE 0: f32 = acc+bias ; 1: bf16 = gelu(acc+bias) ; 2: f32 = xin + g*(acc+bias)
// MODE 3: bf16 partial = acc (split-K over blockIdx.z) ; 4: bf16 = acc+bias
// lB swizzle (both sides): byte_col ^= ((row ^ (row>>2)) & 7) << 4.
template<int MODE>
__global__ __launch_bounds__(256, 4) void k_gemm(
    const u16* __restrict__ A, int lda,
    const float* __restrict__ B0, const float* __restrict__ B1, int ldbN,
    void* __restrict__ out0, void* __restrict__ out1, int ldc,
    const float* __restrict__ b0, const float* __restrict__ b1, int K,
    const float* __restrict__ x0, const float* __restrict__ x1,
    const float* __restrict__ g0, const float* __restrict__ g1,
    u16* __restrict__ part) {
  __shared__ __align__(16) u16 lA[128 * 64];
  __shared__ __align__(16) u16 lB[128 * 64];
  int gx = gridDim.x, gy = gridDim.y, nwg = gx * gy;
  int bid = blockIdx.y * gx + blockIdx.x;
  int sw = (bid & 7) * (nwg >> 3) + (bid >> 3);    // XCD swizzle (nwg%8==0)
  int bx = sw / gy, by = sw - bx * gy;             // by (M) innermost
  int m0 = by * 128, n0 = bx * 128;
  bool txs = (m0 < LT);
  const float* Bf = txs ? B1 : B0;
  const float* bias = txs ? b1 : b0;
  int mr = txs ? m0 : m0 - LT;
  int z = blockIdx.z;
  int Kh = K / (int)gridDim.z;                     // split-K chunk
  int tid = threadIdx.x, lane = tid & 63, wid = tid >> 6;
  int wh = wid >> 1, ww = wid & 1;
  f32x4 acc[4][4] = {};
  const char* Ab = (const char*)(A + (size_t)m0 * lda + (size_t)z * Kh);
  const float* Bb = Bf + (size_t)z * Kh * ldbN + n0;
  int ko = (lane >> 4) * 8, cl = lane & 15;
  int tn = (tid & 31) * 4;                          // B-stage: n within tile
  int tk = (tid >> 5) * 8;                          // B-stage: k within BK
  for (int k0 = 0; k0 < Kh; k0 += 64) {
    // A: async global->LDS (bf16, linear+XOR as before)
#pragma unroll
    for (int i = 0; i < 4; ++i) {
      int o = (i * 256 + tid) * 16;
      int r = o >> 7, cb = o & 127;
      gload16(Ab + (size_t)r * (lda * 2) + k0 * 2 + cb, (char*)lA + o);
    }
    // B: reg-staged transpose+convert from f32 [K][N]
    {
      const float* src = Bb + (size_t)(k0 + tk) * ldbN + tn;
      float4 L[8];
#pragma unroll
      for (int kk = 0; kk < 8; ++kk)
        L[kk] = *(const float4*)(src + (size_t)kk * ldbN);
#pragma unroll
      for (int j = 0; j < 4; ++j) {
        int row = tn + j;
        u16 pk[8] __attribute__((aligned(16)));
#pragma unroll
        for (int kk = 0; kk < 8; ++kk) pk[kk] = f2bf(((const float*)&L[kk])[j]);
        int s = ((row ^ (row >> 2)) & 7) << 4;
        *(uint4*)((char*)lB + row * 128 + ((tk * 2) ^ s)) = *(uint4*)pk;
      }
    }
    __syncthreads();
#pragma unroll
    for (int kk = 0; kk < 64; kk += 32) {
      bf16x8 a[4], b[4];
#pragma unroll
      for (int m = 0; m < 4; ++m)
        a[m] = *(const bf16x8*)&lA[(wh * 64 + m * 16 + cl) * 64 + kk + ko];
#pragma unroll
      for (int n = 0; n < 4; ++n) {
        int row = ww * 64 + n * 16 + cl;
        int s = ((row ^ (row >> 2)) & 7) << 4;
        b[n] = *(const bf16x8*)((const char*)lB + row * 128 + (((kk + ko) * 2) ^ s));
      }
#pragma unroll
      for (int m = 0; m < 4; ++m)
#pragma unroll
        for (int n = 0; n < 4; ++n)
          acc[m][n] = __builtin_amdgcn_mfma_f32_16x16x32_bf16(a[m], b[n], acc[m][n], 0, 0, 0);
    }
    __syncthreads();
  }
  int rg = (lane >> 4) * 4;
#pragma unroll
  for (int m = 0; m < 4; ++m) {
    int r0 = wh * 64 + m * 16 + rg;      // local row in tile
#pragma unroll
    for (int n = 0; n < 4; ++n) {
      int gcol = n0 + ww * 64 + n * 16 + cl;
#pragma unroll
      for (int j = 0; j < 4; ++j) {
        float v = acc[m][n][j];
        if (MODE == 3) {
          part[(size_t)z * (LA * (size_t)HID) + (size_t)(m0 + r0 + j) * ldc + gcol] = f2bf(v);
        } else {
          v += bias[gcol];
          size_t orow = (size_t)(mr + r0 + j);
          if (MODE == 0) {
            ((float*)(txs ? out1 : out0))[orow * ldc + gcol] = v;
          } else if (MODE == 4) {
            ((u16*)(txs ? out1 : out0))[orow * ldc + gcol] = f2bf(v);
          } else if (MODE == 1) {
            // gelu(v) = v * sigmoid(2*z), z = 0.79788456*(v + 0.044715 v^3)
            float z2 = 1.5957691216057308f * (v + 0.044715f * v * v * v);
            ((u16*)(txs ? out1 : out0))[orow * ldc + gcol] =
                f2bf(v / (1.f + __expf(-z2)));
          } else {
            const float* xin = txs ? x1 : x0;
            const float* g = txs ? g1 : g0;
            ((float*)(txs ? out1 : out0))[orow * ldc + gcol] =
                xin[orow * ldc + gcol] + g[gcol] * v;
          }
        }
      }
    }
  }
}

// ---- split-K reduce (bf16 partials, NZ slabs): out = xin + g*(sum+bias) ----
template<int NZ>
__global__ void k_red(const u16* __restrict__ P,
                      const float* __restrict__ bias0, const float* __restrict__ bias1,
                      const float* __restrict__ g0, const float* __restrict__ g1,
                      const float* __restrict__ xi, const float* __restrict__ xt,
                      float* __restrict__ oimg, float* __restrict__ otxt) {
  size_t i = ((size_t)blockIdx.x * 256 + threadIdx.x) * 4;
  const size_t S = (size_t)LA * HID;
  int row = (int)(i >> 11), col = (int)(i & (HID - 1));
  float s0 = 0.f, s1 = 0.f, s2 = 0.f, s3 = 0.f;
#pragma unroll
  for (int z = 0; z < NZ; ++z) {
    ushort4 a = *(const ushort4*)&P[i + (size_t)z * S];
    s0 += bf2f(a.x); s1 += bf2f(a.y); s2 += bf2f(a.z); s3 += bf2f(a.w);
  }
  bool txs = row < LT;
  const float* bias = txs ? bias1 : bias0;
  const float* g = txs ? g1 : g0;
  size_t off = txs ? (size_t)row * HID + col : (size_t)(row - LT) * HID + col;
  const float* xin = (txs ? xt : xi) + off;
  float* out = (txs ? otxt : oimg) + off;
  float4 x = *(const float4*)xin;
  float4 o;
  o.x = x.x + g[col] * (s0 + bias[col]);
  o.y = x.y + g[col + 1] * (s1 + bias[col + 1]);
  o.z = x.z + g[col + 2] * (s2 + bias[col + 2]);
  o.w = x.w + g[col + 3] * (s3 + bias[col + 3]);
  *(float4*)out = o;
}

// ---- qkv post (merged rows, bf16 in): rmsnorm(q,k) + rope(q,k) -> [H][LA][HD] bf16 ----
__global__ void k_qkv_post(const u16* __restrict__ qkv,
                           const float* __restrict__ qsi, const float* __restrict__ ksi,
                           const float* __restrict__ qst, const float* __restrict__ kst,
                           const float* __restrict__ pe,
                           u16* __restrict__ Q, u16* __restrict__ K, u16* __restrict__ V) {
  int h = blockIdx.x, lg = blockIdx.y, lane = threadIdx.x;
  bool txs = lg < LT;
  const float* qs = txs ? qst : qsi;
  const float* ks = txs ? kst : ksi;
  const u16* base = qkv + (size_t)lg * 6144 + h * HD;
  float q0 = bf2f(base[2 * lane]), q1 = bf2f(base[2 * lane + 1]);
  float k0 = bf2f(base[2048 + 2 * lane]), k1 = bf2f(base[2048 + 2 * lane + 1]);
  float v0 = bf2f(base[4096 + 2 * lane]), v1 = bf2f(base[4096 + 2 * lane + 1]);
  float sq = q0 * q0 + q1 * q1, sk = k0 * k0 + k1 * k1;
#pragma unroll
  for (int m = 1; m < 64; m <<= 1) { sq += __shfl_xor(sq, m); sk += __shfl_xor(sk, m); }
  float rq = rsqrtf(sq * (1.f / HD) + 1e-6f), rk = rsqrtf(sk * (1.f / HD) + 1e-6f);
  q0 *= rq * qs[2 * lane]; q1 *= rq * qs[2 * lane + 1];
  k0 *= rk * ks[2 * lane]; k1 *= rk * ks[2 * lane + 1];
  float4 p = *(const float4*)&pe[(size_t)lg * 256 + lane * 4];
  float qa = p.x * q0 + p.y * q1, qb = p.z * q0 + p.w * q1;
  float ka = p.x * k0 + p.y * k1, kb = p.z * k0 + p.w * k1;
  size_t ob = ((size_t)h * LA + lg) * HD + 2 * lane;
  Q[ob] = f2bf(qa); Q[ob + 1] = f2bf(qb);
  K[ob] = f2bf(ka); K[ob + 1] = f2bf(kb);
  V[ob] = f2bf(v0); V[ob + 1] = f2bf(v1);
}

// -------- V [H][LA][HD] -> Vt [H][HD][LA] (bf16) --------
__global__ void k_vtrans(const u16* __restrict__ V, u16* __restrict__ Vt) {
  __shared__ __align__(16) u16 t[64][72];
  int l0 = blockIdx.x * 64, d0 = blockIdx.y * 64, h = blockIdx.z;
  const u16* src = V + (size_t)h * LA * HD;
#pragma unroll
  for (int jj = 0; jj < 2; ++jj) {
    int idx = (jj * 256 + threadIdx.x) * 8;
    int r = idx >> 6, c = idx & 63;
    *(uint4*)&t[r][c] = *(const uint4*)&src[(size_t)(l0 + r) * HD + d0 + c];
  }
  __syncthreads();
  u16* dst = Vt + (size_t)h * HD * LA;
#pragma unroll
  for (int jj = 0; jj < 2; ++jj) {
    int idx = (jj * 256 + threadIdx.x) * 8;
    int r = idx >> 6, c = idx & 63;
    u16 o[8] __attribute__((aligned(16)));
#pragma unroll
    for (int u = 0; u < 8; ++u) o[u] = t[c + u][r];
    *(uint4*)&dst[(size_t)(d0 + r) * LA + l0 + c] = *(uint4*)o;
  }
}

// ---- flash attention v5: QBLK=144, 9 waves, 256 blocks = 1/CU, XCD-owns-heads ----
__global__ __launch_bounds__(576) void k_flash(
    const u16* __restrict__ Q, const u16* __restrict__ Kg,
    const u16* __restrict__ Vt, u16* __restrict__ attn) {
  __shared__ __align__(16) u16 Ks[2][64 * 128];   // [row t][col d], swizzled
  __shared__ __align__(16) u16 Vs[2][128 * 64];   // [row d][col t], swizzled
  __shared__ __align__(16) u16 Ps[9][16 * 64];    // [row q][col t], swizzled
  int bid = blockIdx.y * gridDim.x + blockIdx.x;
  int xcd = bid & 7, j0 = bid >> 3;               // j0 in [0,32)
  int h = xcd * 2 + (j0 >> 4);
  int q0 = (j0 & 15) * 144;
  int tid = threadIdx.x, lane = tid & 63, w = tid >> 6;
  int ko = (lane >> 4) * 8, cl = lane & 15;
  const char* Kb = (const char*)(Kg + (size_t)h * LA * HD);
  const char* Vb = (const char*)(Vt + (size_t)h * HD * LA);
  bf16x8 qf[4];
  {
    const u16* Qr = Q + ((size_t)h * LA + q0 + w * 16 + cl) * HD;
#pragma unroll
    for (int kk = 0; kk < 4; ++kk) qf[kk] = *(const bf16x8*)&Qr[kk * 32 + ko];
  }
  f32x4 oacc[8] = {};
  float mst[4] = {-1e30f, -1e30f, -1e30f, -1e30f};
  float lst[4] = {0.f, 0.f, 0.f, 0.f};

  auto stage = [&](int t0, int buf) {
    if (tid < 512) {
#pragma unroll
      for (int i = 0; i < 2; ++i) {
        int o = (i * 512 + tid) * 16;
        int r = o >> 8, c = o & 255;                 // K tile: 64 rows x 256B
        gload16(Kb + (size_t)(t0 + r) * 256 + (c ^ ((r & 7) << 4)),
                (char*)Ks[buf] + o);
        int r2 = o >> 7, c2 = o & 127;               // V tile: 128 rows x 128B
        gload16(Vb + (size_t)r2 * (LA * 2) + (size_t)t0 * 2 + (c2 ^ ((r2 & 7) << 4)),
                (char*)Vs[buf] + o);
      }
    }
  };

  stage(0, 0);
  __syncthreads();
  for (int t = 0; t < LA / 64; ++t) {
    int buf = t & 1;
    if (t < LA / 64 - 1) stage((t + 1) * 64, buf ^ 1);
    // ---- S = Q K^T ----
    f32x4 sacc[4] = {};
    __builtin_amdgcn_s_setprio(1);
#pragma unroll
    for (int kk = 0; kk < 4; ++kk) {
      int cb = (kk * 32 + ko) * 2;
#pragma unroll
      for (int n = 0; n < 4; ++n) {
        int row = n * 16 + cl;
        bf16x8 bk = *(const bf16x8*)&Ks[buf][row * 128 + ((cb ^ ((row & 7) << 4)) >> 1)];
        sacc[n] = __builtin_amdgcn_mfma_f32_16x16x32_bf16(qf[kk], bk, sacc[n], 0, 0, 0);
      }
    }
    __builtin_amdgcn_s_setprio(0);
    // ---- online softmax (defer-max THR=8) ----
    const float scale = 0.08838834764831845f;
    float mx[4];
#pragma unroll
    for (int j = 0; j < 4; ++j) {
      float m1 = -1e30f;
#pragma unroll
      for (int n = 0; n < 4; ++n) { sacc[n][j] *= scale; m1 = fmaxf(m1, sacc[n][j]); }
#pragma unroll
      for (int m = 1; m < 16; m <<= 1) m1 = fmaxf(m1, __shfl_xor(m1, m));
      mx[j] = m1;
    }
    float dmax = fmaxf(fmaxf(mx[0] - mst[0], mx[1] - mst[1]),
                       fmaxf(mx[2] - mst[2], mx[3] - mst[3]));
    if (!__all(dmax <= 8.f)) {
#pragma unroll
      for (int j = 0; j < 4; ++j) {
        float mnew = fmaxf(mst[j], mx[j]);
        float alpha = __expf(mst[j] - mnew);
        lst[j] *= alpha; mst[j] = mnew;
#pragma unroll
        for (int nd = 0; nd < 8; ++nd) oacc[nd][j] *= alpha;
      }
    }
    float p[4][4];
#pragma unroll
    for (int j = 0; j < 4; ++j) {
      float s = 0.f;
#pragma unroll
      for (int n = 0; n < 4; ++n) { p[n][j] = __expf(sacc[n][j] - mst[j]); s += p[n][j]; }
#pragma unroll
      for (int m = 1; m < 16; m <<= 1) s += __shfl_xor(s, m);
      lst[j] += s;
    }
    // ---- P -> LDS (swizzled, per-wave region) ----
#pragma unroll
    for (int j = 0; j < 4; ++j) {
      int pr = (lane >> 4) * 4 + j;
#pragma unroll
      for (int n = 0; n < 4; ++n)
        Ps[w][pr * 64 + ((((n * 16 + cl) * 2) ^ ((pr & 7) << 4)) >> 1)] = f2bf(p[n][j]);
    }
    // ---- O += P V ----
    __builtin_amdgcn_s_setprio(1);
#pragma unroll
    for (int kk = 0; kk < 64; kk += 32) {
      int cb = (kk + ko) * 2;
      bf16x8 ap = *(const bf16x8*)&Ps[w][cl * 64 + ((cb ^ ((cl & 7) << 4)) >> 1)];
#pragma unroll
      for (int nd = 0; nd < 8; ++nd) {
        int vr = nd * 16 + cl;
        bf16x8 bv = *(const bf16x8*)&Vs[buf][vr * 64 + ((cb ^ ((vr & 7) << 4)) >> 1)];
        oacc[nd] = __builtin_amdgcn_mfma_f32_16x16x32_bf16(ap, bv, oacc[nd], 0, 0, 0);
      }
    }
    __builtin_amdgcn_s_setprio(0);
    __syncthreads();
  }
#pragma unroll
  for (int j = 0; j < 4; ++j) {
    int lrow = q0 + w * 16 + (lane >> 4) * 4 + j;
    float inv = 1.f / lst[j];
#pragma unroll
    for (int nd = 0; nd < 8; ++nd)
      attn[(size_t)lrow * HID + h * HD + nd * 16 + cl] = f2bf(oacc[nd][j] * inv);
  }
}

extern "C" void kernel_launch(void* const* d_in, const int* in_sizes, int n_in,
                              void* d_out, int out_size, void* d_ws, size_t ws_size,
                              hipStream_t stream) {
  const float* img = (const float*)d_in[0];
  const float* txt = (const float*)d_in[1];
  const float* vec = (const float*)d_in[2];
  const float* pe  = (const float*)d_in[3];
  const float* imod_w = (const float*)d_in[4];
  const float* imod_b = (const float*)d_in[5];
  const float* iqkv_w = (const float*)d_in[6];
  const float* iqkv_b = (const float*)d_in[7];
  const float* iq_s   = (const float*)d_in[8];
  const float* ik_s   = (const float*)d_in[9];
  const float* iproj_w = (const float*)d_in[10];
  const float* iproj_b = (const float*)d_in[11];
  const float* imlp_w1 = (const float*)d_in[12];
  const float* imlp_b1 = (const float*)d_in[13];
  const float* imlp_w2 = (const float*)d_in[14];
  const float* imlp_b2 = (const float*)d_in[15];
  const float* tmod_w = (const float*)d_in[16];
  const float* tmod_b = (const float*)d_in[17];
  const float* tqkv_w = (const float*)d_in[18];
  const float* tqkv_b = (const float*)d_in[19];
  const float* tq_s   = (const float*)d_in[20];
  const float* tk_s   = (const float*)d_in[21];
  const float* tproj_w = (const float*)d_in[22];
  const float* tproj_b = (const float*)d_in[23];
  const float* tmlp_w1 = (const float*)d_in[24];
  const float* tmlp_b1 = (const float*)d_in[25];
  const float* tmlp_w2 = (const float*)d_in[26];
  const float* tmlp_b2 = (const float*)d_in[27];
  (void)in_sizes; (void)n_in; (void)out_size; (void)ws_size;

  float* oimg = (float*)d_out;                    // [LI][HID]
  float* otxt = oimg + (size_t)LI * HID;          // [LT][HID]

  char* p = (char*)d_ws;
  auto alloc = [&](size_t b) { char* r = p; p += (b + 255) & ~(size_t)255; return r; };
  float* part = (float*)alloc((size_t)16 * MODW * 4);
  float* mod  = (float*)alloc((size_t)2 * MODW * 4);     // [img; txt] x 6 x 2048
  u16*  xm    = (u16*)alloc((size_t)LA * HID * 2);       // merged [txt; img]
  u16*  qkvr  = (u16*)alloc((size_t)LA * 6144 * 2);      // merged [txt; img], bf16
  u16*  Qb    = (u16*)alloc((size_t)NH * LA * HD * 2);
  u16*  Kb    = (u16*)alloc((size_t)NH * LA * HD * 2);
  u16*  Vb    = (u16*)alloc((size_t)NH * LA * HD * 2);
  u16*  Vtb   = (u16*)alloc((size_t)NH * LA * HD * 2);
  u16*  attn  = (u16*)alloc((size_t)LA * HID * 2);       // merged [txt; img]
  u16*  hb    = (u16*)alloc((size_t)LA * 8192 * 2);      // merged [txt; img]
  u16*  kpart = (u16*)alloc((size_t)4 * LA * HID * 2);   // split-K partials (bf16)

  const float* MI = mod;           // sh1, sc1, g1, sh2, sc2, g2 (stride 2048)
  const float* MT = mod + MODW;

  // modulation vectors
  k_mod_partial<<<dim3(48, 8, 2), 256, 0, stream>>>(vec, imod_w, tmod_w, part);
  k_mod_reduce<<<dim3(96), 256, 0, stream>>>(part, imod_b, tmod_b, mod);

  // LN + mod (pass 1) -> xm merged
  k_ln_mod<<<dim3(LA), 256, 0, stream>>>(img, txt, MI, MI + 2048, MT, MT + 2048, xm);

  // QKV (merged txt+img): 864 blocks, B = f32 weights direct
  k_gemm<4><<<dim3(48, 18), 256, 0, stream>>>(xm, 2048, iqkv_w, tqkv_w, 6144,
      qkvr + (size_t)LT * 6144, qkvr, 6144, iqkv_b, tqkv_b, 2048,
      nullptr, nullptr, nullptr, nullptr, nullptr);

  // rmsnorm + rope -> Q,K,V ; V transpose
  k_qkv_post<<<dim3(NH, LA), 64, 0, stream>>>(qkvr, iq_s, ik_s, tq_s, tk_s, pe, Qb, Kb, Vb);
  k_vtrans<<<dim3(36, 2, NH), 256, 0, stream>>>(Vb, Vtb);

  // attention: 256 blocks, exactly 1 per CU, heads pinned to XCDs
  k_flash<<<dim3(16, NH), 576, 0, stream>>>(Qb, Kb, Vtb, attn);

  // proj: unsplit, fused gated residual -> d_out (288 blocks)
  k_gemm<2><<<dim3(16, 18), 256, 0, stream>>>(attn, 2048, iproj_w, tproj_w, 2048,
      oimg, otxt, 2048, iproj_b, tproj_b, 2048,
      img, txt, MI + 4096, MT + 4096, nullptr);

  // LN + mod (pass 2)
  k_ln_mod<<<dim3(LA), 256, 0, stream>>>(oimg, otxt, MI + 6144, MI + 8192,
                                         MT + 6144, MT + 8192, xm);

  // MLP1 + gelu fused -> hb bf16: 1152 blocks
  k_gemm<1><<<dim3(64, 18), 256, 0, stream>>>(xm, 2048, imlp_w1, tmlp_w1, 8192,
      hb + (size_t)LT * 8192, hb, 8192, imlp_b1, tmlp_b1, 2048,
      nullptr, nullptr, nullptr, nullptr, nullptr);

  // MLP2: split-K=4 (1152 blocks) -> bf16 partials, reduce + final residual
  k_gemm<3><<<dim3(16, 18, 4), 256, 0, stream>>>(hb, 8192, imlp_w2, tmlp_w2, 2048,
      nullptr, nullptr, 2048, nullptr, nullptr, 8192,
      nullptr, nullptr, nullptr, nullptr, kpart);
  k_red<4><<<dim3(4608), 256, 0, stream>>>(kpart, imlp_b2, tmlp_b2,
      MI + 10240, MT + 10240, oimg, otxt, oimg, otxt);
}

// Round 15
// 651.653 us; speedup vs baseline: 1.2887x; 1.2887x over previous
//
#include <hip/hip_runtime.h>
#include <math.h>

typedef unsigned short u16;
typedef short bf16x8 __attribute__((ext_vector_type(8)));
typedef float f32x4 __attribute__((ext_vector_type(4)));

#define HID 2048
#define NH 16
#define HD 128
#define LI 2048
#define LT 256
#define LA 2304
#define MODW 12288

__device__ __forceinline__ u16 f2bf(float f) {
  unsigned int u = __float_as_uint(f);
  u += 0x7fff + ((u >> 16) & 1);   // round-to-nearest-even
  return (u16)(u >> 16);
}
__device__ __forceinline__ float bf2f(u16 b) {
  return __uint_as_float(((unsigned int)b) << 16);
}

__device__ __forceinline__ void gload16(const void* g, void* l) {
  __builtin_amdgcn_global_load_lds(
      (const __attribute__((address_space(1))) unsigned int*)g,
      (__attribute__((address_space(3))) unsigned int*)l, 16, 0, 0);
}

// ---------------- modulation GEMV: silu(vec) @ mod_w ----------------
__global__ void k_mod_partial(const float* __restrict__ vec,
                              const float* __restrict__ wi,
                              const float* __restrict__ wt,
                              float* __restrict__ part) {
  __shared__ float sv[256];
  int j = blockIdx.x * 256 + threadIdx.x;
  int k0 = blockIdx.y * 256;
  const float* w = blockIdx.z ? wt : wi;
  float v = vec[k0 + threadIdx.x];
  sv[threadIdx.x] = v / (1.f + expf(-v));
  __syncthreads();
  float acc = 0.f;
  for (int kk = 0; kk < 256; ++kk)
    acc += sv[kk] * w[(size_t)(k0 + kk) * MODW + j];
  part[(size_t)(blockIdx.z * 8 + blockIdx.y) * MODW + j] = acc;
}

__global__ void k_mod_reduce(const float* __restrict__ part,
                             const float* __restrict__ bi,
                             const float* __restrict__ bt,
                             float* __restrict__ mod) {
  int i = blockIdx.x * 256 + threadIdx.x;   // 0..24575
  int s = i / MODW, j = i % MODW;
  const float* b = s ? bt : bi;
  float v = b[j];
#pragma unroll
  for (int c = 0; c < 8; ++c) v += part[(size_t)(s * 8 + c) * MODW + j];
  mod[i] = v;
}

// ------- LayerNorm + (1+sc)*x + sh -> bf16, merged [txt; img] rows -------
__global__ void k_ln_mod(const float* __restrict__ xi, const float* __restrict__ xt,
                         const float* __restrict__ shi, const float* __restrict__ sci,
                         const float* __restrict__ sht, const float* __restrict__ sct,
                         u16* __restrict__ out) {
  int r = blockIdx.x;                 // merged row: txt first
  bool txs = r < LT;
  const float* xr = txs ? (xt + (size_t)r * HID) : (xi + (size_t)(r - LT) * HID);
  const float* sh = txs ? sht : shi;
  const float* sc = txs ? sct : sci;
  float4 v0 = ((const float4*)xr)[threadIdx.x * 2];
  float4 v1 = ((const float4*)xr)[threadIdx.x * 2 + 1];
  float s1 = v0.x + v0.y + v0.z + v0.w + v1.x + v1.y + v1.z + v1.w;
  float s2 = v0.x * v0.x + v0.y * v0.y + v0.z * v0.z + v0.w * v0.w +
             v1.x * v1.x + v1.y * v1.y + v1.z * v1.z + v1.w * v1.w;
#pragma unroll
  for (int m = 1; m < 64; m <<= 1) { s1 += __shfl_xor(s1, m); s2 += __shfl_xor(s2, m); }
  __shared__ float red[8];
  int wid = threadIdx.x >> 6;
  if ((threadIdx.x & 63) == 0) { red[wid] = s1; red[4 + wid] = s2; }
  __syncthreads();
  float tot  = red[0] + red[1] + red[2] + red[3];
  float tot2 = red[4] + red[5] + red[6] + red[7];
  float mu = tot * (1.f / HID);
  float var = tot2 * (1.f / HID) - mu * mu;
  float rs = rsqrtf(var + 1e-6f);
  int c = threadIdx.x * 8;
  float v[8] = {v0.x, v0.y, v0.z, v0.w, v1.x, v1.y, v1.z, v1.w};
  u16 o[8] __attribute__((aligned(16)));
#pragma unroll
  for (int u = 0; u < 8; ++u)
    o[u] = f2bf((v[u] - mu) * rs * (1.f + sc[c + u]) + sh[c + u]);
  *(uint4*)&out[(size_t)r * HID + c] = *(uint4*)o;
}

// ---------- transpose+convert: f32 [K][N] -> bf16 [N][K], dual-source ----------
__global__ void k_tconv(const float* __restrict__ srcI, const float* __restrict__ srcT,
                        u16* __restrict__ dstI, u16* __restrict__ dstT,
                        int K, int N) {
  __shared__ __align__(16) float t[64][65];
  const float* src = blockIdx.z ? srcT : srcI;
  u16* dst = blockIdx.z ? dstT : dstI;
  int n0 = blockIdx.x * 64, k0 = blockIdx.y * 64;
  int tr = threadIdx.x >> 4;
  int tc = (threadIdx.x & 15) * 4;
#pragma unroll
  for (int i = 0; i < 4; ++i) {
    int r = i * 16 + tr;
    float4 v = *(const float4*)&src[(size_t)(k0 + r) * N + n0 + tc];
    t[r][tc] = v.x; t[r][tc + 1] = v.y; t[r][tc + 2] = v.z; t[r][tc + 3] = v.w;
  }
  __syncthreads();
#pragma unroll
  for (int i = 0; i < 4; ++i) {
    int nr = i * 16 + tr;
    ushort4 o;
    o.x = f2bf(t[tc][nr]); o.y = f2bf(t[tc + 1][nr]);
    o.z = f2bf(t[tc + 2][nr]); o.w = f2bf(t[tc + 3][nr]);
    *(ushort4*)&dst[(size_t)(n0 + nr) * K + k0 + tc] = o;
  }
}

// ------------- 128x128 GEMM (m97 structure, 4 waves, 4-5 blocks/CU) -------------
// MODE 0: f32 = acc+bias ; 1: bf16 = gelu(acc+bias) ; 2: f32 = xin + g*(acc+bias)
// MODE 3: bf16 partial = acc (split-K over blockIdx.z) ; 4: bf16 = acc+bias
// Swizzle: XCD gets contiguous sw range with by (M) INNERMOST -> concurrent
// window per XCD = all 18 by x ~8 bx: B live set = 8 panels (4 MB, L2-fits);
// the re-fetched matrix is A (the smaller one).
template<int MODE>
__global__ __launch_bounds__(256, 4) void k_gemm(
    const u16* __restrict__ A, int lda,
    const u16* __restrict__ B0, const u16* __restrict__ B1, int ldb,
    void* __restrict__ out0, void* __restrict__ out1, int ldc,
    const float* __restrict__ b0, const float* __restrict__ b1, int K,
    const float* __restrict__ x0, const float* __restrict__ x1,
    const float* __restrict__ g0, const float* __restrict__ g1,
    u16* __restrict__ part) {
  __shared__ __align__(16) u16 lA[128 * 64];
  __shared__ __align__(16) u16 lB[128 * 64];
  int gx = gridDim.x, gy = gridDim.y, nwg = gx * gy;
  int bid = blockIdx.y * gx + blockIdx.x;
  int sw = (bid & 7) * (nwg >> 3) + (bid >> 3);    // XCD swizzle (nwg%8==0)
  int bx = sw / gy, by = sw - bx * gy;             // by innermost
  int m0 = by * 128, n0 = bx * 128;
  bool txs = (m0 < LT);
  const u16* Bt = txs ? B1 : B0;
  const float* bias = txs ? b1 : b0;
  int mr = txs ? m0 : m0 - LT;
  int z = blockIdx.z;
  int Kh = K / (int)gridDim.z;                     // split-K chunk
  int tid = threadIdx.x, lane = tid & 63, wid = tid >> 6;
  int wh = wid >> 1, ww = wid & 1;
  f32x4 acc[4][4] = {};
  const char* Ab = (const char*)(A + (size_t)m0 * lda + (size_t)z * Kh);
  const char* Bb = (const char*)(Bt + (size_t)n0 * ldb + (size_t)z * Kh);
  int ko = (lane >> 4) * 8, cl = lane & 15;
  for (int k0 = 0; k0 < Kh; k0 += 64) {
#pragma unroll
    for (int i = 0; i < 4; ++i) {
      int o = (i * 256 + tid) * 16;
      int r = o >> 7, cb = o & 127;
      gload16(Ab + (size_t)r * (lda * 2) + k0 * 2 + cb, (char*)lA + o);
      gload16(Bb + (size_t)r * (ldb * 2) + k0 * 2 + cb, (char*)lB + o);
    }
    __syncthreads();
#pragma unroll
    for (int kk = 0; kk < 64; kk += 32) {
      bf16x8 a[4], b[4];
#pragma unroll
      for (int m = 0; m < 4; ++m)
        a[m] = *(const bf16x8*)&lA[(wh * 64 + m * 16 + cl) * 64 + kk + ko];
#pragma unroll
      for (int n = 0; n < 4; ++n)
        b[n] = *(const bf16x8*)&lB[(ww * 64 + n * 16 + cl) * 64 + kk + ko];
#pragma unroll
      for (int m = 0; m < 4; ++m)
#pragma unroll
        for (int n = 0; n < 4; ++n)
          acc[m][n] = __builtin_amdgcn_mfma_f32_16x16x32_bf16(a[m], b[n], acc[m][n], 0, 0, 0);
    }
    __syncthreads();
  }
  int rg = (lane >> 4) * 4;
#pragma unroll
  for (int m = 0; m < 4; ++m) {
    int r0 = wh * 64 + m * 16 + rg;      // local row in tile
#pragma unroll
    for (int n = 0; n < 4; ++n) {
      int gcol = n0 + ww * 64 + n * 16 + cl;
#pragma unroll
      for (int j = 0; j < 4; ++j) {
        float v = acc[m][n][j];
        if (MODE == 3) {
          part[(size_t)z * (LA * (size_t)HID) + (size_t)(m0 + r0 + j) * ldc + gcol] = f2bf(v);
        } else {
          v += bias[gcol];
          size_t orow = (size_t)(mr + r0 + j);
          if (MODE == 0) {
            ((float*)(txs ? out1 : out0))[orow * ldc + gcol] = v;
          } else if (MODE == 4) {
            ((u16*)(txs ? out1 : out0))[orow * ldc + gcol] = f2bf(v);
          } else if (MODE == 1) {
            // gelu(v) = v * sigmoid(2*z), z = 0.79788456*(v + 0.044715 v^3)
            float z2 = 1.5957691216057308f * (v + 0.044715f * v * v * v);
            ((u16*)(txs ? out1 : out0))[orow * ldc + gcol] =
                f2bf(v / (1.f + __expf(-z2)));
          } else {
            const float* xin = txs ? x1 : x0;
            const float* g = txs ? g1 : g0;
            ((float*)(txs ? out1 : out0))[orow * ldc + gcol] =
                xin[orow * ldc + gcol] + g[gcol] * v;
          }
        }
      }
    }
  }
}

// ---- split-K reduce (bf16 partials, NZ slabs): out = xin + g*(sum+bias) ----
template<int NZ>
__global__ void k_red(const u16* __restrict__ P,
                      const float* __restrict__ bias0, const float* __restrict__ bias1,
                      const float* __restrict__ g0, const float* __restrict__ g1,
                      const float* __restrict__ xi, const float* __restrict__ xt,
                      float* __restrict__ oimg, float* __restrict__ otxt) {
  size_t i = ((size_t)blockIdx.x * 256 + threadIdx.x) * 4;
  const size_t S = (size_t)LA * HID;
  int row = (int)(i >> 11), col = (int)(i & (HID - 1));
  float s0 = 0.f, s1 = 0.f, s2 = 0.f, s3 = 0.f;
#pragma unroll
  for (int z = 0; z < NZ; ++z) {
    ushort4 a = *(const ushort4*)&P[i + (size_t)z * S];
    s0 += bf2f(a.x); s1 += bf2f(a.y); s2 += bf2f(a.z); s3 += bf2f(a.w);
  }
  bool txs = row < LT;
  const float* bias = txs ? bias1 : bias0;
  const float* g = txs ? g1 : g0;
  size_t off = txs ? (size_t)row * HID + col : (size_t)(row - LT) * HID + col;
  const float* xin = (txs ? xt : xi) + off;
  float* out = (txs ? otxt : oimg) + off;
  float4 x = *(const float4*)xin;
  float4 o;
  o.x = x.x + g[col] * (s0 + bias[col]);
  o.y = x.y + g[col + 1] * (s1 + bias[col + 1]);
  o.z = x.z + g[col + 2] * (s2 + bias[col + 2]);
  o.w = x.w + g[col + 3] * (s3 + bias[col + 3]);
  *(float4*)out = o;
}

// ---- qkv post (merged rows, bf16 in): rmsnorm(q,k) + rope(q,k) -> [H][LA][HD] bf16 ----
__global__ void k_qkv_post(const u16* __restrict__ qkv,
                           const float* __restrict__ qsi, const float* __restrict__ ksi,
                           const float* __restrict__ qst, const float* __restrict__ kst,
                           const float* __restrict__ pe,
                           u16* __restrict__ Q, u16* __restrict__ K, u16* __restrict__ V) {
  int h = blockIdx.x, lg = blockIdx.y, lane = threadIdx.x;
  bool txs = lg < LT;
  const float* qs = txs ? qst : qsi;
  const float* ks = txs ? kst : ksi;
  const u16* base = qkv + (size_t)lg * 6144 + h * HD;
  float q0 = bf2f(base[2 * lane]), q1 = bf2f(base[2 * lane + 1]);
  float k0 = bf2f(base[2048 + 2 * lane]), k1 = bf2f(base[2048 + 2 * lane + 1]);
  float v0 = bf2f(base[4096 + 2 * lane]), v1 = bf2f(base[4096 + 2 * lane + 1]);
  float sq = q0 * q0 + q1 * q1, sk = k0 * k0 + k1 * k1;
#pragma unroll
  for (int m = 1; m < 64; m <<= 1) { sq += __shfl_xor(sq, m); sk += __shfl_xor(sk, m); }
  float rq = rsqrtf(sq * (1.f / HD) + 1e-6f), rk = rsqrtf(sk * (1.f / HD) + 1e-6f);
  q0 *= rq * qs[2 * lane]; q1 *= rq * qs[2 * lane + 1];
  k0 *= rk * ks[2 * lane]; k1 *= rk * ks[2 * lane + 1];
  float4 p = *(const float4*)&pe[(size_t)lg * 256 + lane * 4];
  float qa = p.x * q0 + p.y * q1, qb = p.z * q0 + p.w * q1;
  float ka = p.x * k0 + p.y * k1, kb = p.z * k0 + p.w * k1;
  size_t ob = ((size_t)h * LA + lg) * HD + 2 * lane;
  Q[ob] = f2bf(qa); Q[ob + 1] = f2bf(qb);
  K[ob] = f2bf(ka); K[ob + 1] = f2bf(kb);
  V[ob] = f2bf(v0); V[ob + 1] = f2bf(v1);
}

// -------- V [H][LA][HD] -> Vt [H][HD][LA] (bf16) --------
__global__ void k_vtrans(const u16* __restrict__ V, u16* __restrict__ Vt) {
  __shared__ __align__(16) u16 t[64][72];
  int l0 = blockIdx.x * 64, d0 = blockIdx.y * 64, h = blockIdx.z;
  const u16* src = V + (size_t)h * LA * HD;
#pragma unroll
  for (int jj = 0; jj < 2; ++jj) {
    int idx = (jj * 256 + threadIdx.x) * 8;
    int r = idx >> 6, c = idx & 63;
    *(uint4*)&t[r][c] = *(const uint4*)&src[(size_t)(l0 + r) * HD + d0 + c];
  }
  __syncthreads();
  u16* dst = Vt + (size_t)h * HD * LA;
#pragma unroll
  for (int jj = 0; jj < 2; ++jj) {
    int idx = (jj * 256 + threadIdx.x) * 8;
    int r = idx >> 6, c = idx & 63;
    u16 o[8] __attribute__((aligned(16)));
#pragma unroll
    for (int u = 0; u < 8; ++u) o[u] = t[c + u][r];
    *(uint4*)&dst[(size_t)(d0 + r) * LA + l0 + c] = *(uint4*)o;
  }
}

// ---- flash attention v5: QBLK=144, 9 waves, 256 blocks = 1/CU, XCD-owns-heads ----
__global__ __launch_bounds__(576) void k_flash(
    const u16* __restrict__ Q, const u16* __restrict__ Kg,
    const u16* __restrict__ Vt, u16* __restrict__ attn) {
  __shared__ __align__(16) u16 Ks[2][64 * 128];   // [row t][col d], swizzled
  __shared__ __align__(16) u16 Vs[2][128 * 64];   // [row d][col t], swizzled
  __shared__ __align__(16) u16 Ps[9][16 * 64];    // [row q][col t], swizzled
  int bid = blockIdx.y * gridDim.x + blockIdx.x;
  int xcd = bid & 7, j0 = bid >> 3;               // j0 in [0,32)
  int h = xcd * 2 + (j0 >> 4);
  int q0 = (j0 & 15) * 144;
  int tid = threadIdx.x, lane = tid & 63, w = tid >> 6;
  int ko = (lane >> 4) * 8, cl = lane & 15;
  const char* Kb = (const char*)(Kg + (size_t)h * LA * HD);
  const char* Vb = (const char*)(Vt + (size_t)h * HD * LA);
  bf16x8 qf[4];
  {
    const u16* Qr = Q + ((size_t)h * LA + q0 + w * 16 + cl) * HD;
#pragma unroll
    for (int kk = 0; kk < 4; ++kk) qf[kk] = *(const bf16x8*)&Qr[kk * 32 + ko];
  }
  f32x4 oacc[8] = {};
  float mst[4] = {-1e30f, -1e30f, -1e30f, -1e30f};
  float lst[4] = {0.f, 0.f, 0.f, 0.f};

  auto stage = [&](int t0, int buf) {
    if (tid < 512) {
#pragma unroll
      for (int i = 0; i < 2; ++i) {
        int o = (i * 512 + tid) * 16;
        int r = o >> 8, c = o & 255;                 // K tile: 64 rows x 256B
        gload16(Kb + (size_t)(t0 + r) * 256 + (c ^ ((r & 7) << 4)),
                (char*)Ks[buf] + o);
        int r2 = o >> 7, c2 = o & 127;               // V tile: 128 rows x 128B
        gload16(Vb + (size_t)r2 * (LA * 2) + (size_t)t0 * 2 + (c2 ^ ((r2 & 7) << 4)),
                (char*)Vs[buf] + o);
      }
    }
  };

  stage(0, 0);
  __syncthreads();
  for (int t = 0; t < LA / 64; ++t) {
    int buf = t & 1;
    if (t < LA / 64 - 1) stage((t + 1) * 64, buf ^ 1);
    // ---- S = Q K^T ----
    f32x4 sacc[4] = {};
    __builtin_amdgcn_s_setprio(1);
#pragma unroll
    for (int kk = 0; kk < 4; ++kk) {
      int cb = (kk * 32 + ko) * 2;
#pragma unroll
      for (int n = 0; n < 4; ++n) {
        int row = n * 16 + cl;
        bf16x8 bk = *(const bf16x8*)&Ks[buf][row * 128 + ((cb ^ ((row & 7) << 4)) >> 1)];
        sacc[n] = __builtin_amdgcn_mfma_f32_16x16x32_bf16(qf[kk], bk, sacc[n], 0, 0, 0);
      }
    }
    __builtin_amdgcn_s_setprio(0);
    // ---- online softmax (defer-max THR=8) ----
    const float scale = 0.08838834764831845f;
    float mx[4];
#pragma unroll
    for (int j = 0; j < 4; ++j) {
      float m1 = -1e30f;
#pragma unroll
      for (int n = 0; n < 4; ++n) { sacc[n][j] *= scale; m1 = fmaxf(m1, sacc[n][j]); }
#pragma unroll
      for (int m = 1; m < 16; m <<= 1) m1 = fmaxf(m1, __shfl_xor(m1, m));
      mx[j] = m1;
    }
    float dmax = fmaxf(fmaxf(mx[0] - mst[0], mx[1] - mst[1]),
                       fmaxf(mx[2] - mst[2], mx[3] - mst[3]));
    if (!__all(dmax <= 8.f)) {
#pragma unroll
      for (int j = 0; j < 4; ++j) {
        float mnew = fmaxf(mst[j], mx[j]);
        float alpha = __expf(mst[j] - mnew);
        lst[j] *= alpha; mst[j] = mnew;
#pragma unroll
        for (int nd = 0; nd < 8; ++nd) oacc[nd][j] *= alpha;
      }
    }
    float p[4][4];
#pragma unroll
    for (int j = 0; j < 4; ++j) {
      float s = 0.f;
#pragma unroll
      for (int n = 0; n < 4; ++n) { p[n][j] = __expf(sacc[n][j] - mst[j]); s += p[n][j]; }
#pragma unroll
      for (int m = 1; m < 16; m <<= 1) s += __shfl_xor(s, m);
      lst[j] += s;
    }
    // ---- P -> LDS (swizzled, per-wave region) ----
#pragma unroll
    for (int j = 0; j < 4; ++j) {
      int pr = (lane >> 4) * 4 + j;
#pragma unroll
      for (int n = 0; n < 4; ++n)
        Ps[w][pr * 64 + ((((n * 16 + cl) * 2) ^ ((pr & 7) << 4)) >> 1)] = f2bf(p[n][j]);
    }
    // ---- O += P V ----
    __builtin_amdgcn_s_setprio(1);
#pragma unroll
    for (int kk = 0; kk < 64; kk += 32) {
      int cb = (kk + ko) * 2;
      bf16x8 ap = *(const bf16x8*)&Ps[w][cl * 64 + ((cb ^ ((cl & 7) << 4)) >> 1)];
#pragma unroll
      for (int nd = 0; nd < 8; ++nd) {
        int vr = nd * 16 + cl;
        bf16x8 bv = *(const bf16x8*)&Vs[buf][vr * 64 + ((cb ^ ((vr & 7) << 4)) >> 1)];
        oacc[nd] = __builtin_amdgcn_mfma_f32_16x16x32_bf16(ap, bv, oacc[nd], 0, 0, 0);
      }
    }
    __builtin_amdgcn_s_setprio(0);
    __syncthreads();
  }
#pragma unroll
  for (int j = 0; j < 4; ++j) {
    int lrow = q0 + w * 16 + (lane >> 4) * 4 + j;
    float inv = 1.f / lst[j];
#pragma unroll
    for (int nd = 0; nd < 8; ++nd)
      attn[(size_t)lrow * HID + h * HD + nd * 16 + cl] = f2bf(oacc[nd][j] * inv);
  }
}

extern "C" void kernel_launch(void* const* d_in, const int* in_sizes, int n_in,
                              void* d_out, int out_size, void* d_ws, size_t ws_size,
                              hipStream_t stream) {
  const float* img = (const float*)d_in[0];
  const float* txt = (const float*)d_in[1];
  const float* vec = (const float*)d_in[2];
  const float* pe  = (const float*)d_in[3];
  const float* imod_w = (const float*)d_in[4];
  const float* imod_b = (const float*)d_in[5];
  const float* iqkv_w = (const float*)d_in[6];
  const float* iqkv_b = (const float*)d_in[7];
  const float* iq_s   = (const float*)d_in[8];
  const float* ik_s   = (const float*)d_in[9];
  const float* iproj_w = (const float*)d_in[10];
  const float* iproj_b = (const float*)d_in[11];
  const float* imlp_w1 = (const float*)d_in[12];
  const float* imlp_b1 = (const float*)d_in[13];
  const float* imlp_w2 = (const float*)d_in[14];
  const float* imlp_b2 = (const float*)d_in[15];
  const float* tmod_w = (const float*)d_in[16];
  const float* tmod_b = (const float*)d_in[17];
  const float* tqkv_w = (const float*)d_in[18];
  const float* tqkv_b = (const float*)d_in[19];
  const float* tq_s   = (const float*)d_in[20];
  const float* tk_s   = (const float*)d_in[21];
  const float* tproj_w = (const float*)d_in[22];
  const float* tproj_b = (const float*)d_in[23];
  const float* tmlp_w1 = (const float*)d_in[24];
  const float* tmlp_b1 = (const float*)d_in[25];
  const float* tmlp_w2 = (const float*)d_in[26];
  const float* tmlp_b2 = (const float*)d_in[27];
  (void)in_sizes; (void)n_in; (void)out_size; (void)ws_size;

  float* oimg = (float*)d_out;                    // [LI][HID]
  float* otxt = oimg + (size_t)LI * HID;          // [LT][HID]

  char* p = (char*)d_ws;
  auto alloc = [&](size_t b) { char* r = p; p += (b + 255) & ~(size_t)255; return r; };
  float* part = (float*)alloc((size_t)16 * MODW * 4);
  float* mod  = (float*)alloc((size_t)2 * MODW * 4);     // [img; txt] x 6 x 2048
  u16*  xm    = (u16*)alloc((size_t)LA * HID * 2);       // merged [txt; img]
  u16*  wt_i  = (u16*)alloc((size_t)8192 * 2048 * 2);
  u16*  wt_t  = (u16*)alloc((size_t)8192 * 2048 * 2);
  u16*  qkvr  = (u16*)alloc((size_t)LA * 6144 * 2);      // merged [txt; img], bf16
  u16*  Qb    = (u16*)alloc((size_t)NH * LA * HD * 2);
  u16*  Kb    = (u16*)alloc((size_t)NH * LA * HD * 2);
  u16*  Vb    = (u16*)alloc((size_t)NH * LA * HD * 2);
  u16*  Vtb   = (u16*)alloc((size_t)NH * LA * HD * 2);
  u16*  attn  = (u16*)alloc((size_t)LA * HID * 2);       // merged [txt; img]
  u16*  hb    = (u16*)alloc((size_t)LA * 8192 * 2);      // merged [txt; img]
  u16*  kpart = (u16*)alloc((size_t)4 * LA * HID * 2);   // split-K partials (bf16)

  const float* MI = mod;           // sh1, sc1, g1, sh2, sc2, g2 (stride 2048)
  const float* MT = mod + MODW;

  // modulation vectors
  k_mod_partial<<<dim3(48, 8, 2), 256, 0, stream>>>(vec, imod_w, tmod_w, part);
  k_mod_reduce<<<dim3(96), 256, 0, stream>>>(part, imod_b, tmod_b, mod);

  // LN + mod (pass 1) -> xm merged
  k_ln_mod<<<dim3(LA), 256, 0, stream>>>(img, txt, MI, MI + 2048, MT, MT + 2048, xm);

  // QKV (merged txt+img): 864 blocks, bf16 out
  k_tconv<<<dim3(96, 32, 2), 256, 0, stream>>>(iqkv_w, tqkv_w, wt_i, wt_t, 2048, 6144);
  k_gemm<4><<<dim3(48, 18), 256, 0, stream>>>(xm, 2048, wt_i, wt_t, 2048,
      qkvr + (size_t)LT * 6144, qkvr, 6144, iqkv_b, tqkv_b, 2048,
      nullptr, nullptr, nullptr, nullptr, nullptr);

  // rmsnorm + rope -> Q,K,V ; V transpose
  k_qkv_post<<<dim3(NH, LA), 64, 0, stream>>>(qkvr, iq_s, ik_s, tq_s, tk_s, pe, Qb, Kb, Vb);
  k_vtrans<<<dim3(36, 2, NH), 256, 0, stream>>>(Vb, Vtb);

  // attention: 256 blocks, exactly 1 per CU, heads pinned to XCDs
  k_flash<<<dim3(16, NH), 576, 0, stream>>>(Qb, Kb, Vtb, attn);

  // proj: unsplit, fused gated residual -> d_out (288 blocks)
  k_tconv<<<dim3(32, 32, 2), 256, 0, stream>>>(iproj_w, tproj_w, wt_i, wt_t, 2048, 2048);
  k_gemm<2><<<dim3(16, 18), 256, 0, stream>>>(attn, 2048, wt_i, wt_t, 2048,
      oimg, otxt, 2048, iproj_b, tproj_b, 2048,
      img, txt, MI + 4096, MT + 4096, nullptr);

  // LN + mod (pass 2)
  k_ln_mod<<<dim3(LA), 256, 0, stream>>>(oimg, otxt, MI + 6144, MI + 8192,
                                         MT + 6144, MT + 8192, xm);

  // MLP1 + gelu fused -> hb bf16: 1152 blocks
  k_tconv<<<dim3(128, 32, 2), 256, 0, stream>>>(imlp_w1, tmlp_w1, wt_i, wt_t, 2048, 8192);
  k_gemm<1><<<dim3(64, 18), 256, 0, stream>>>(xm, 2048, wt_i, wt_t, 2048,
      hb + (size_t)LT * 8192, hb, 8192, imlp_b1, tmlp_b1, 2048,
      nullptr, nullptr, nullptr, nullptr, nullptr);

  // MLP2: split-K=4 (1152 blocks = 4.5/CU) -> bf16 partials, reduce + residual
  k_tconv<<<dim3(32, 128, 2), 256, 0, stream>>>(imlp_w2, tmlp_w2, wt_i, wt_t, 8192, 2048);
  k_gemm<3><<<dim3(16, 18, 4), 256, 0, stream>>>(hb, 8192, wt_i, wt_t, 8192,
      nullptr, nullptr, 2048, nullptr, nullptr, 8192,
      nullptr, nullptr, nullptr, nullptr, kpart);
  k_red<4><<<dim3(4608), 256, 0, stream>>>(kpart, imlp_b2, tmlp_b2,
      MI + 10240, MT + 10240, oimg, otxt, oimg, otxt);
}